// Round 12
// baseline (505.255 us; speedup 1.0000x reference)
//
#include <hip/hip_runtime.h>
#include <math.h>

// NormalConsistencyLoss: B=4, N=8192, D=3, K=16, fp32 in/out (scalar out).
// [hist/prefix/scatter] bucket each cloud by x (256 monotone buckets).
// [select_kernel] exact 16-NN: outward 64-chunk sweep over bucketed points,
//   window = sqrt(min(thrA, t16)) + margin (shrinks as t16 tightens);
//   analytic radius filter + r11's wave-shared serial lex (d2,origidx)
//   insert; sentinel-validated redo (x2.5; final round = full scan).
//   Bit-identical selection to lax.top_k.
// [normal_kernel] thread-per-query covariance + faithful LAPACK ssyevd port.
// [loss_partial/loss_final] 1 - mean(dot).

#define NPTS 8192
#define NB   4
#define QPW  4

// ---------------- LAPACK single-precision ports (sign-faithful) ----------------

__device__ __forceinline__ float slapy2f(float x, float y){
#pragma clang fp contract(off)
  float xa = fabsf(x), ya = fabsf(y);
  float w = fmaxf(xa, ya), z = fminf(xa, ya);
  if (z == 0.f) return w;
  float t = z / w;
  return w * sqrtf(1.f + t*t);
}

// LAPACK >= 3.10 slartg
__device__ __forceinline__ void slartgf(float f, float g, float& c, float& s, float& r){
#pragma clang fp contract(off)
  const float safmin = 1.17549435e-38f;
  const float safmax = 8.50705917e37f;
  const float rtmin  = 1.08420217e-19f;
  const float rtmax  = 6.52318604e18f;
  if (g == 0.f){ c = 1.f; s = 0.f; r = f; }
  else if (f == 0.f){ c = 0.f; s = copysignf(1.f, g); r = fabsf(g); }
  else {
    float f1 = fabsf(f), g1 = fabsf(g);
    if (f1 > rtmin && f1 < rtmax && g1 > rtmin && g1 < rtmax){
      float d = sqrtf(f*f + g*g);
      c = f1 / d;
      r = copysignf(d, f);
      s = g / r;
    } else {
      float u = fminf(safmax, fmaxf(safmin, fmaxf(f1, g1)));
      float fs = f/u, gs = g/u;
      float d = sqrtf(fs*fs + gs*gs);
      c = fabsf(fs)/d;
      r = copysignf(d, f);
      r = r*u;
      s = g/r;
    }
  }
}

__device__ __forceinline__ void slaev2f(float a, float b, float cc,
                                        float& rt1, float& rt2, float& cs1, float& sn1){
#pragma clang fp contract(off)
  float sm  = a + cc;
  float df  = a - cc;
  float adf = fabsf(df);
  float tb  = b + b;
  float ab  = fabsf(tb);
  float acmx, acmn;
  if (fabsf(a) > fabsf(cc)){ acmx = a; acmn = cc; } else { acmx = cc; acmn = a; }
  float rt;
  if (adf > ab){ float t = ab/adf; rt = adf*sqrtf(1.f + t*t); }
  else if (adf < ab){ float t = adf/ab; rt = ab*sqrtf(1.f + t*t); }
  else rt = ab*sqrtf(2.f);
  int sgn1;
  if (sm < 0.f){ rt1 = 0.5f*(sm - rt); sgn1 = -1; rt2 = (acmx/rt1)*acmn - (b/rt1)*b; }
  else if (sm > 0.f){ rt1 = 0.5f*(sm + rt); sgn1 = 1; rt2 = (acmx/rt1)*acmn - (b/rt1)*b; }
  else { rt1 = 0.5f*rt; rt2 = -0.5f*rt; sgn1 = 1; }
  int sgn2; float cs;
  if (df >= 0.f){ cs = df + rt; sgn2 = 1; } else { cs = df - rt; sgn2 = -1; }
  float acs = fabsf(cs);
  if (acs > ab){ float ct = -tb/cs; sn1 = 1.f/sqrtf(1.f + ct*ct); cs1 = ct*sn1; }
  else {
    if (ab == 0.f){ cs1 = 1.f; sn1 = 0.f; }
    else { float tn = -cs/tb; cs1 = 1.f/sqrtf(1.f + tn*tn); sn1 = tn*cs1; }
  }
  if (sgn1 == sgn2){ float tn = cs1; cs1 = -sn1; sn1 = tn; }
}

__device__ __forceinline__ void rot2(float z[3][3], int ja, float c, float s){
#pragma clang fp contract(off)
  #pragma unroll
  for (int i = 0; i < 3; ++i){
    float t1 = z[i][ja+1];
    float t0 = z[i][ja];
    z[i][ja+1] = c*t1 - s*t0;
    z[i][ja]   = s*t1 + c*t0;
  }
}

// Faithful port of LAPACK ssteqr('I', n=3, d, e, z)
__device__ __noinline__ void ssteqr3(float* d, float* e, float z[3][3]){
#pragma clang fp contract(off)
  const float eps    = 5.96046448e-08f;
  const float eps2   = 3.55271368e-15f;
  const float safmin = 1.17549435e-38f;
  const float ssfmax = 3.07445735e+18f;
  const float ssfmin = 3.05175781e-05f;
  const int n = 3;
  float cw[2], sw[2];
  int nmaxit, jtot, l1, l, lsv, lend, lendsv, m, iscale, i, j, ii, k;
  float anorm, p, g, r, c, s, f, b, rt1, rt2, tst, mul;

  for (i = 0; i < 3; ++i) for (j = 0; j < 3; ++j) z[i][j] = (i == j) ? 1.f : 0.f;
  nmaxit = n*30; jtot = 0; l1 = 1; m = 0; iscale = 0; anorm = 0.f;
  lsv = 1; lendsv = 1; lend = 1; l = 1;

L10:
  if (l1 > n) goto L160;
  if (l1 > 1) e[l1-2] = 0.f;
  if (l1 <= n-1){
    for (m = l1; m <= n-1; ++m){
      tst = fabsf(e[m-1]);
      if (tst == 0.f) goto L30;
      if (tst <= (sqrtf(fabsf(d[m-1]))*sqrtf(fabsf(d[m])))*eps){ e[m-1] = 0.f; goto L30; }
    }
  }
  m = n;
L30:
  l = l1; lsv = l; lend = m; lendsv = lend; l1 = m + 1;
  if (lend == l) goto L10;
  anorm = 0.f;
  for (i = l; i <= lend; ++i)   anorm = fmaxf(anorm, fabsf(d[i-1]));
  for (i = l; i <= lend-1; ++i) anorm = fmaxf(anorm, fabsf(e[i-1]));
  iscale = 0;
  if (anorm == 0.f) goto L10;
  if (anorm > ssfmax){
    iscale = 1; mul = ssfmax/anorm;
    for (i = l; i <= lend; ++i)   d[i-1] *= mul;
    for (i = l; i <= lend-1; ++i) e[i-1] *= mul;
  } else if (anorm < ssfmin){
    iscale = 2; mul = ssfmin/anorm;
    for (i = l; i <= lend; ++i)   d[i-1] *= mul;
    for (i = l; i <= lend-1; ++i) e[i-1] *= mul;
  }
  if (fabsf(d[lend-1]) < fabsf(d[l-1])){ lend = lsv; l = lendsv; }

  if (lend > l){
L40:
    if (l != lend){
      for (m = l; m <= lend-1; ++m){
        tst = fabsf(e[m-1]); tst = tst*tst;
        if (tst <= (eps2*fabsf(d[m-1]))*fabsf(d[m]) + safmin) goto L60;
      }
    }
    m = lend;
L60:
    if (m < lend) e[m-1] = 0.f;
    p = d[l-1];
    if (m == l) goto L80;
    if (m == l+1){
      slaev2f(d[l-1], e[l-1], d[l], rt1, rt2, c, s);
      rot2(z, l-1, c, s);
      d[l-1] = rt1; d[l] = rt2; e[l-1] = 0.f;
      l += 2;
      if (l <= lend) goto L40;
      goto L140;
    }
    if (jtot == nmaxit) goto L140;
    jtot++;
    g = (d[l] - p)/(2.f*e[l-1]);
    r = slapy2f(g, 1.f);
    g = d[m-1] - p + (e[l-1]/(g + copysignf(r, g)));
    s = 1.f; c = 1.f; p = 0.f;
    for (i = m-1; i >= l; --i){
      f = s*e[i-1];
      b = c*e[i-1];
      slartgf(g, f, c, s, r);
      if (i != m-1) e[i] = r;
      g = d[i] - p;
      r = (d[i-1] - g)*s + 2.f*c*b;
      p = s*r;
      d[i] = g + p;
      g = c*r - b;
      cw[i-l] = c; sw[i-l] = -s;
    }
    for (j = m-l; j >= 1; --j) rot2(z, l+j-2, cw[j-1], sw[j-1]);
    d[l-1] = d[l-1] - p;
    e[l-1] = g;
    goto L40;
L80:
    d[l-1] = p;
    l += 1;
    if (l <= lend) goto L40;
    goto L140;
  } else {
L90:
    if (l != lend){
      for (m = l; m >= lend+1; --m){
        tst = fabsf(e[m-2]); tst = tst*tst;
        if (tst <= (eps2*fabsf(d[m-1]))*fabsf(d[m-2]) + safmin) goto L110;
      }
    }
    m = lend;
L110:
    if (m > lend) e[m-2] = 0.f;
    p = d[l-1];
    if (m == l) goto L130;
    if (m == l-1){
      slaev2f(d[l-2], e[l-2], d[l-1], rt1, rt2, c, s);
      rot2(z, l-2, c, s);
      d[l-2] = rt1; d[l-1] = rt2; e[l-2] = 0.f;
      l -= 2;
      if (l >= lend) goto L90;
      goto L140;
    }
    if (jtot == nmaxit) goto L140;
    jtot++;
    g = (d[l-2] - p)/(2.f*e[l-2]);
    r = slapy2f(g, 1.f);
    g = d[m-1] - p + (e[l-2]/(g + copysignf(r, g)));
    s = 1.f; c = 1.f; p = 0.f;
    for (i = m; i <= l-1; ++i){
      f = s*e[i-1];
      b = c*e[i-1];
      slartgf(g, f, c, s, r);
      if (i != m) e[i-2] = r;
      g = d[i-1] - p;
      r = (d[i] - g)*s + 2.f*c*b;
      p = s*r;
      d[i-1] = g + p;
      g = c*r - b;
      cw[i-m] = c; sw[i-m] = s;
    }
    for (j = 1; j <= l-m; ++j) rot2(z, m+j-2, cw[j-1], sw[j-1]);
    d[l-1] = d[l-1] - p;
    e[l-2] = g;
    goto L90;
L130:
    d[l-1] = p;
    l -= 1;
    if (l >= lend) goto L90;
    goto L140;
  }
L140:
  if (iscale == 1){
    mul = anorm/ssfmax;
    for (i = lsv; i <= lendsv; ++i)   d[i-1] *= mul;
    for (i = lsv; i <= lendsv-1; ++i) e[i-1] *= mul;
  } else if (iscale == 2){
    mul = anorm/ssfmin;
    for (i = lsv; i <= lendsv; ++i)   d[i-1] *= mul;
    for (i = lsv; i <= lendsv-1; ++i) e[i-1] *= mul;
  }
  if (jtot < nmaxit) goto L10;
  return;
L160:
  for (ii = 2; ii <= n; ++ii){
    i = ii - 1; k = i; p = d[i-1];
    for (j = ii; j <= n; ++j){
      if (d[j-1] < p){ k = j; p = d[j-1]; }
    }
    if (k != i){
      d[k-1] = d[i-1]; d[i-1] = p;
      for (j = 0; j < 3; ++j){ float t = z[j][i-1]; z[j][i-1] = z[j][k-1]; z[j][k-1] = t; }
    }
  }
}

__device__ __noinline__ void eigh3_normal(float a11, float a21, float a31,
                                          float a22, float a32, float a33,
                                          float* out3){
#pragma clang fp contract(off)
  float d[3], e[2], z[3][3];
  float tau1 = 0.f, v2 = 0.f;
  float alpha = a21;
  float xnorm = fabsf(a31);
  if (xnorm == 0.f){
    e[0] = alpha;
    tau1 = 0.f;
  } else {
    float beta = -copysignf(slapy2f(alpha, xnorm), alpha);
    tau1 = (beta - alpha)/beta;
    v2 = a31*(1.f/(alpha - beta));
    float x1 = tau1*a22 + tau1*(a32*v2);
    float x2 = tau1*a32 + (tau1*v2)*a33;
    float al = -0.5f*tau1*(x1 + x2*v2);
    float w1 = x1 + al;
    float w2 = x2 + al*v2;
    a22 = a22 - w1 - w1;
    a32 = a32 - v2*w1 - w2;
    a33 = a33 - v2*w2 - w2*v2;
    e[0] = beta;
  }
  e[1] = a32;
  d[0] = a11; d[1] = a22; d[2] = a33;
  ssteqr3(d, e, z);
  if (tau1 != 0.f){
    #pragma unroll
    for (int jj = 0; jj < 3; ++jj){
      float wj  = z[1][jj] + v2*z[2][jj];
      float tmp = tau1*wj;
      z[1][jj] = z[1][jj] - tmp;
      z[2][jj] = z[2][jj] - v2*tmp;
    }
  }
  out3[0] = z[0][0]; out3[1] = z[1][0]; out3[2] = z[2][0];
}

// ---------------- helpers ----------------

__device__ __forceinline__ float sq3f(float x, float y, float z){
#pragma clang fp contract(off)
  return x*x + y*y + z*z;
}

__device__ __forceinline__ float d2f(float qs, float qx, float qy, float qz, float4 c){
#pragma clang fp contract(off)
  float dot = qx*c.x + qy*c.y + qz*c.z;
  return (qs + c.w) - 2.f*dot;
}

__device__ __forceinline__ int bucket_of(float x){
#pragma clang fp contract(off)
  return (int)fminf(fmaxf((x + 4.0f)*32.0f, 0.0f), 255.0f);   // monotone in x
}

// ---------------- bucket-build kernels ----------------

__global__ __launch_bounds__(256) void hist_kernel(const float* __restrict__ pred,
                                                   const float* __restrict__ gt,
                                                   int* __restrict__ hist){
  int i = blockIdx.x*256 + threadIdx.x;        // 0..65535
  int cloud = i >> 13;
  int p = i & 8191;
  const float* base = ((cloud >> 2) ? gt : pred) + (size_t)(cloud & 3)*(NPTS*3);
  float x = base[p*3+0];
  atomicAdd(&hist[cloud*256 + bucket_of(x)], 1);
}

__global__ void prefix_kernel(const int* __restrict__ hist, int* __restrict__ bstart){
  __shared__ int buf[256];
  const int t = threadIdx.x;
  for (int c = 0; c < 8; ++c){
    buf[t] = hist[c*256 + t];
    __syncthreads();
    for (int off = 1; off < 256; off <<= 1){
      int u = (t >= off) ? buf[t - off] : 0;
      __syncthreads();
      buf[t] += u;
      __syncthreads();
    }
    if (t == 0) bstart[c*257] = 0;
    bstart[c*257 + t + 1] = buf[t];
    __syncthreads();
  }
}

__global__ __launch_bounds__(256) void scatter_kernel(const float* __restrict__ pred,
                                                      const float* __restrict__ gt,
                                                      const int* __restrict__ bstart,
                                                      int* __restrict__ bfill,
                                                      float4* __restrict__ bpts,
                                                      unsigned int* __restrict__ binfo){
#pragma clang fp contract(off)
  int i = blockIdx.x*256 + threadIdx.x;
  int cloud = i >> 13;
  int p = i & 8191;
  const float* base = ((cloud >> 2) ? gt : pred) + (size_t)(cloud & 3)*(NPTS*3);
  float x = base[p*3+0], y = base[p*3+1], z = base[p*3+2];
  int b = bucket_of(x);
  int pos = bstart[cloud*257 + b] + atomicAdd(&bfill[cloud*256 + b], 1);
  bpts [(size_t)cloud*NPTS + pos] = make_float4(x, y, z, sq3f(x, y, z));
  binfo[(size_t)cloud*NPTS + pos] = ((unsigned int)p << 8) | (unsigned int)b;
}

// ---------------- select: bucketed sweep, exact lex top-16 ----------------

// One wave = 4 queries (bucket-adjacent positions). Outward 64-chunk sweep
// (right then left) from the home chunk; per-chunk stop when the frontier
// bucket's edge exceeds the wave window max_k(x_q +/- (sqrt(min(thrA,t16))
// + 1e-2)). t16 only shrinks => stop-safe. Bucket 0 / 255 edges = +-inf
// (clamped tails). Lists/EV-insert/redo = r11 (proven exact).
__global__ __launch_bounds__(256) void select_kernel(const float4* __restrict__ bpts,
                                                     const unsigned int* __restrict__ binfo,
                                                     unsigned short* __restrict__ topk){
#pragma clang fp contract(off)
  const int tid  = threadIdx.x;
  const int lane = tid & 63;
  const int g    = blockIdx.x*4 + (tid >> 6);   // wave id 0..16383
  const int qbase = g*QPW;                      // bucketed position space
  const int pc   = qbase >> 13;                 // cloud 0..7
  const float4*       __restrict__ bp = bpts  + (size_t)pc*NPTS;
  const unsigned int* __restrict__ bf = binfo + (size_t)pc*NPTS;
  const int q0 = qbase & 8191;

  float4 qv[QPW];
  #pragma unroll
  for (int k = 0; k < QPW; ++k) qv[k] = bp[q0 + k];

  float thrA[QPW];
  #pragma unroll
  for (int k = 0; k < QPW; ++k)
    thrA[k] = fminf(0.0599f * __expf(qv[k].w * 0.33333334f), 0.8f);

  float bd[QPW]; int bi[QPW]; float t16[QPW]; int tI[QPW]; bool done[QPW];
  #pragma unroll
  for (int k = 0; k < QPW; ++k) done[k] = false;

  const int pR0 = q0 & ~63;

#define EV_INSERT(K, ddv, civv, passv) {                                      \
    unsigned long long m = __ballot(passv);                                   \
    while (m){                                                                \
      int s = __ffsll(m) - 1;                                                 \
      m &= m - 1;                                                             \
      float dds = __shfl((ddv), s);                                           \
      int cis = __shfl((civv), s);                                            \
      if ((dds < t16[K]) || (dds == t16[K] && cis < tI[K])){                  \
        bool less = (bd[K] < dds) || (bd[K] == dds && bi[K] < cis);           \
        unsigned long long lm = __ballot(less) & 0xFFFFull;                   \
        int pos = __popcll(lm);                                               \
        float bup = __shfl_up(bd[K], 1);                                      \
        int   iup = __shfl_up(bi[K], 1);                                      \
        bool tn = (lane == pos);                                              \
        bool tu = (lane > pos) && (lane < 16);                                \
        bd[K] = tn ? dds : (tu ? bup : bd[K]);                                \
        bi[K] = tn ? cis : (tu ? iup : bi[K]);                                \
        t16[K] = __shfl(bd[K], 15);                                           \
        tI[K]  = __shfl(bi[K], 15);                                           \
      }                                                                       \
    }                                                                         \
  }

#define WIN_BOUNDS() {                                                        \
    xmax = -3.0e38f; xmin = 3.0e38f;                                          \
    _Pragma("unroll")                                                         \
    for (int k = 0; k < QPW; ++k) if (!done[k]){                              \
      float rr = sqrtf(fminf(thrA[k], t16[k])) + 1.0e-2f;                     \
      xmax = fmaxf(xmax, qv[k].x + rr);                                       \
      xmin = fminf(xmin, qv[k].x - rr);                                       \
    }                                                                         \
  }

#define PROCESS_CHUNK(CS) {                                                   \
    int pos = (CS) + lane;                                                    \
    bool vmask = (pos >= 0) && (pos < NPTS);                                  \
    int cpos = vmask ? pos : 0;                                               \
    float4 cd = bp[cpos];                                                     \
    unsigned int bnf = bf[cpos];                                              \
    int civ = (int)(((bnf >> 8) << 13) | (unsigned int)cpos);                 \
    _Pragma("unroll")                                                         \
    for (int k = 0; k < QPW; ++k){                                            \
      float dd = d2f(qv[k].w, qv[k].x, qv[k].y, qv[k].z, cd);                 \
      bool pass = vmask && (!done[k]) && (dd <= fminf(thrA[k], t16[k]));      \
      EV_INSERT(k, dd, civ, pass)                                             \
    }                                                                         \
  }

  for (int round = 0; round < 7; ++round){
    #pragma unroll
    for (int k = 0; k < QPW; ++k) if (!done[k]){
      bd[k] = 3.0e38f; bi[k] = 0x7fffffff; t16[k] = 3.0e38f; tI[k] = 0x7fffffff;
    }
    float xmax, xmin;
    // right sweep (includes home chunk)
    int pR = pR0;
    while (pR < NPTS){
      int jR = (int)(bf[pR] & 255u);
      WIN_BOUNDS();
      float eLo = (jR == 0) ? -3.0e38f : ((float)jR * 0.03125f - 4.0f);
      if (eLo > xmax) break;
      PROCESS_CHUNK(pR);
      pR += 64;
    }
    // left sweep
    int pL = pR0;
    while (pL > 0){
      int jL = (int)(bf[pL - 1] & 255u);
      WIN_BOUNDS();
      float eHi = (jL == 255) ? 3.0e38f : ((float)(jL + 1) * 0.03125f - 4.0f);
      if (eHi < xmin) break;
      PROCESS_CHUNK(pL - 64);
      pL -= 64;
    }
    // validation / redo
    bool anyUn = false;
    #pragma unroll
    for (int k = 0; k < QPW; ++k) if (!done[k]){
      if (t16[k] < 2.9e38f) done[k] = true;
      else { anyUn = true; thrA[k] = (round >= 5) ? 1.0e30f : thrA[k]*2.5f + 1.0e-3f; }
    }
    if (!anyUn) break;
  }
#undef PROCESS_CHUNK
#undef WIN_BOUNDS
#undef EV_INSERT

  if (lane < 16){
    #pragma unroll
    for (int k = 0; k < QPW; ++k){
      int oq = (int)(bf[q0 + k] >> 8);           // original query index
      topk[((size_t)pc*NPTS + oq)*16 + lane] = (unsigned short)(bi[k] & 8191);
    }
  }
}

// Thread per query: gather 16 neighbors by bucketed position (lex order),
// covariance, eigh.
__global__ __launch_bounds__(256) void normal_kernel(const float4* __restrict__ bpts,
                                                     const unsigned short* __restrict__ topk,
                                                     float* __restrict__ normals){
#pragma clang fp contract(off)
  const int gq = blockIdx.x*256 + threadIdx.x;   // 0..65535 (original order)
  const int pc = gq >> 13;
  const float4* __restrict__ bp = bpts + (size_t)pc*NPTS;
  const unsigned short* __restrict__ tk = topk + (size_t)gq*16;

  float gxx[16], gyy[16], gzz[16];
  #pragma unroll
  for (int r = 0; r < 16; ++r){
    float4 p = bp[tk[r]];
    gxx[r] = p.x; gyy[r] = p.y; gzz[r] = p.z;
  }
  float mx = 0.f, my = 0.f, mz = 0.f;
  #pragma unroll
  for (int r = 0; r < 16; ++r){ mx += gxx[r]; my += gyy[r]; mz += gzz[r]; }
  mx *= 0.0625f; my *= 0.0625f; mz *= 0.0625f;

  float c00=0.f, c10=0.f, c20=0.f, c11=0.f, c21=0.f, c22=0.f;
  #pragma unroll
  for (int r = 0; r < 16; ++r){
    float cx = gxx[r]-mx, cy = gyy[r]-my, cz = gzz[r]-mz;
    c00 += cx*cx; c10 += cy*cx; c20 += cz*cx;
    c11 += cy*cy; c21 += cz*cy; c22 += cz*cz;
  }
  c00 *= 0.0625f; c10 *= 0.0625f; c20 *= 0.0625f;
  c11 *= 0.0625f; c21 *= 0.0625f; c22 *= 0.0625f;

  float nrm[3];
  eigh3_normal(c00, c10, c20, c11, c21, c22, nrm);

  float* o = normals + (size_t)gq*3;
  o[0] = nrm[0]; o[1] = nrm[1]; o[2] = nrm[2];
}

// ---------------- loss ----------------

__global__ __launch_bounds__(256) void loss_partial(const float* __restrict__ normals,
                                                    float* __restrict__ partials){
  __shared__ float red[256];
  const float4* a4 = (const float4*)normals;                        // 24576 float4
  const float4* g4 = (const float4*)(normals + (size_t)NB*NPTS*3);
  float acc = 0.f;
  for (int i = blockIdx.x*256 + threadIdx.x; i < 24576; i += 64*256){
    float4 a = a4[i], g = g4[i];
    acc += a.x*g.x + a.y*g.y + a.z*g.z + a.w*g.w;
  }
  red[threadIdx.x] = acc;
  __syncthreads();
  for (int sft = 128; sft > 0; sft >>= 1){
    if (threadIdx.x < sft) red[threadIdx.x] += red[threadIdx.x + sft];
    __syncthreads();
  }
  if (threadIdx.x == 0) partials[blockIdx.x] = red[0];
}

__global__ void loss_final(const float* __restrict__ partials,
                           float* __restrict__ out){
  float v = partials[threadIdx.x];
  #pragma unroll
  for (int s = 32; s > 0; s >>= 1) v += __shfl_down(v, s, 64);
  if (threadIdx.x == 0) out[0] = 1.f - v*(1.f/32768.f);
}

extern "C" void kernel_launch(void* const* d_in, const int* in_sizes, int n_in,
                              void* d_out, int out_size, void* d_ws, size_t ws_size,
                              hipStream_t stream) {
  const float* pred = (const float*)d_in[0];
  const float* gt   = (const float*)d_in[1];
  // ws layout (bytes):
  //   0        normals   786432 (196608 f)
  //   786432   partials  256
  //   786688   hist      8192   (8*256 int)   -- memset 0 with bfill
  //   794880   bfill     8192   (8*256 int)
  //   803072   bstart    8224   (8*257 int)
  //   811296   bpts      1048576 (65536 float4, 16B-aligned)
  //   1859872  binfo     262144 (65536 uint)
  //   2122016  topk      2097152 (1048576 ushort)
  //   total ~4.02 MB
  char* w = (char*)d_ws;
  float*          normals  = (float*)(w);
  float*          partials = (float*)(w + 786432);
  int*            hist     = (int*)(w + 786688);
  int*            bfill    = (int*)(w + 794880);
  int*            bstart   = (int*)(w + 803072);
  float4*         bpts     = (float4*)(w + 811296);
  unsigned int*   binfo    = (unsigned int*)(w + 1859872);
  unsigned short* topk     = (unsigned short*)(w + 2122016);

  hipMemsetAsync(w + 786688, 0, 16384, stream);          // hist + bfill
  hist_kernel   <<<256,  256, 0, stream>>>(pred, gt, hist);
  prefix_kernel <<<1,    256, 0, stream>>>(hist, bstart);
  scatter_kernel<<<256,  256, 0, stream>>>(pred, gt, bstart, bfill, bpts, binfo);
  select_kernel <<<4096, 256, 0, stream>>>(bpts, binfo, topk);
  normal_kernel <<<256,  256, 0, stream>>>(bpts, topk, normals);
  loss_partial  <<<64,   256, 0, stream>>>(normals, partials);
  loss_final    <<<1,     64, 0, stream>>>(partials, (float*)d_out);
}

// Round 13
// 378.185 us; speedup vs baseline: 1.3360x; 1.3360x over previous
//
#include <hip/hip_runtime.h>
#include <math.h>

// NormalConsistencyLoss: B=4, N=8192, D=3, K=16, fp32 in/out (scalar out).
// [pack_kernel]   clouds -> float4(x,y,z,sq).
// [select_kernel] exact 16-NN: analytic radius filter (lambda=32) + wave-shared
//   serial lex (d2,idx) insert (r8-proven); sentinel-validated BAND redo
//   (rescan only thrA_old < dd <= thrA_new; x2.5, 7 rounds -> full-scan
//   guarantee). 4 queries/wave. Bit-identical to lax.top_k.
// [normal_kernel] thread-per-query covariance + faithful LAPACK ssyevd port.
// [loss_partial/loss_final] 1 - mean(dot).

#define NPTS 8192
#define NB   4
#define QPW  4

// ---------------- LAPACK single-precision ports (sign-faithful) ----------------

__device__ __forceinline__ float slapy2f(float x, float y){
#pragma clang fp contract(off)
  float xa = fabsf(x), ya = fabsf(y);
  float w = fmaxf(xa, ya), z = fminf(xa, ya);
  if (z == 0.f) return w;
  float t = z / w;
  return w * sqrtf(1.f + t*t);
}

// LAPACK >= 3.10 slartg
__device__ __forceinline__ void slartgf(float f, float g, float& c, float& s, float& r){
#pragma clang fp contract(off)
  const float safmin = 1.17549435e-38f;
  const float safmax = 8.50705917e37f;
  const float rtmin  = 1.08420217e-19f;
  const float rtmax  = 6.52318604e18f;
  if (g == 0.f){ c = 1.f; s = 0.f; r = f; }
  else if (f == 0.f){ c = 0.f; s = copysignf(1.f, g); r = fabsf(g); }
  else {
    float f1 = fabsf(f), g1 = fabsf(g);
    if (f1 > rtmin && f1 < rtmax && g1 > rtmin && g1 < rtmax){
      float d = sqrtf(f*f + g*g);
      c = f1 / d;
      r = copysignf(d, f);
      s = g / r;
    } else {
      float u = fminf(safmax, fmaxf(safmin, fmaxf(f1, g1)));
      float fs = f/u, gs = g/u;
      float d = sqrtf(fs*fs + gs*gs);
      c = fabsf(fs)/d;
      r = copysignf(d, f);
      r = r*u;
      s = g/r;
    }
  }
}

__device__ __forceinline__ void slaev2f(float a, float b, float cc,
                                        float& rt1, float& rt2, float& cs1, float& sn1){
#pragma clang fp contract(off)
  float sm  = a + cc;
  float df  = a - cc;
  float adf = fabsf(df);
  float tb  = b + b;
  float ab  = fabsf(tb);
  float acmx, acmn;
  if (fabsf(a) > fabsf(cc)){ acmx = a; acmn = cc; } else { acmx = cc; acmn = a; }
  float rt;
  if (adf > ab){ float t = ab/adf; rt = adf*sqrtf(1.f + t*t); }
  else if (adf < ab){ float t = adf/ab; rt = ab*sqrtf(1.f + t*t); }
  else rt = ab*sqrtf(2.f);
  int sgn1;
  if (sm < 0.f){ rt1 = 0.5f*(sm - rt); sgn1 = -1; rt2 = (acmx/rt1)*acmn - (b/rt1)*b; }
  else if (sm > 0.f){ rt1 = 0.5f*(sm + rt); sgn1 = 1; rt2 = (acmx/rt1)*acmn - (b/rt1)*b; }
  else { rt1 = 0.5f*rt; rt2 = -0.5f*rt; sgn1 = 1; }
  int sgn2; float cs;
  if (df >= 0.f){ cs = df + rt; sgn2 = 1; } else { cs = df - rt; sgn2 = -1; }
  float acs = fabsf(cs);
  if (acs > ab){ float ct = -tb/cs; sn1 = 1.f/sqrtf(1.f + ct*ct); cs1 = ct*sn1; }
  else {
    if (ab == 0.f){ cs1 = 1.f; sn1 = 0.f; }
    else { float tn = -cs/tb; cs1 = 1.f/sqrtf(1.f + tn*tn); sn1 = tn*cs1; }
  }
  if (sgn1 == sgn2){ float tn = cs1; cs1 = -sn1; sn1 = tn; }
}

__device__ __forceinline__ void rot2(float z[3][3], int ja, float c, float s){
#pragma clang fp contract(off)
  #pragma unroll
  for (int i = 0; i < 3; ++i){
    float t1 = z[i][ja+1];
    float t0 = z[i][ja];
    z[i][ja+1] = c*t1 - s*t0;
    z[i][ja]   = s*t1 + c*t0;
  }
}

// Faithful port of LAPACK ssteqr('I', n=3, d, e, z)
__device__ __noinline__ void ssteqr3(float* d, float* e, float z[3][3]){
#pragma clang fp contract(off)
  const float eps    = 5.96046448e-08f;
  const float eps2   = 3.55271368e-15f;
  const float safmin = 1.17549435e-38f;
  const float ssfmax = 3.07445735e+18f;
  const float ssfmin = 3.05175781e-05f;
  const int n = 3;
  float cw[2], sw[2];
  int nmaxit, jtot, l1, l, lsv, lend, lendsv, m, iscale, i, j, ii, k;
  float anorm, p, g, r, c, s, f, b, rt1, rt2, tst, mul;

  for (i = 0; i < 3; ++i) for (j = 0; j < 3; ++j) z[i][j] = (i == j) ? 1.f : 0.f;
  nmaxit = n*30; jtot = 0; l1 = 1; m = 0; iscale = 0; anorm = 0.f;
  lsv = 1; lendsv = 1; lend = 1; l = 1;

L10:
  if (l1 > n) goto L160;
  if (l1 > 1) e[l1-2] = 0.f;
  if (l1 <= n-1){
    for (m = l1; m <= n-1; ++m){
      tst = fabsf(e[m-1]);
      if (tst == 0.f) goto L30;
      if (tst <= (sqrtf(fabsf(d[m-1]))*sqrtf(fabsf(d[m])))*eps){ e[m-1] = 0.f; goto L30; }
    }
  }
  m = n;
L30:
  l = l1; lsv = l; lend = m; lendsv = lend; l1 = m + 1;
  if (lend == l) goto L10;
  anorm = 0.f;
  for (i = l; i <= lend; ++i)   anorm = fmaxf(anorm, fabsf(d[i-1]));
  for (i = l; i <= lend-1; ++i) anorm = fmaxf(anorm, fabsf(e[i-1]));
  iscale = 0;
  if (anorm == 0.f) goto L10;
  if (anorm > ssfmax){
    iscale = 1; mul = ssfmax/anorm;
    for (i = l; i <= lend; ++i)   d[i-1] *= mul;
    for (i = l; i <= lend-1; ++i) e[i-1] *= mul;
  } else if (anorm < ssfmin){
    iscale = 2; mul = ssfmin/anorm;
    for (i = l; i <= lend; ++i)   d[i-1] *= mul;
    for (i = l; i <= lend-1; ++i) e[i-1] *= mul;
  }
  if (fabsf(d[lend-1]) < fabsf(d[l-1])){ lend = lsv; l = lendsv; }

  if (lend > l){
L40:
    if (l != lend){
      for (m = l; m <= lend-1; ++m){
        tst = fabsf(e[m-1]); tst = tst*tst;
        if (tst <= (eps2*fabsf(d[m-1]))*fabsf(d[m]) + safmin) goto L60;
      }
    }
    m = lend;
L60:
    if (m < lend) e[m-1] = 0.f;
    p = d[l-1];
    if (m == l) goto L80;
    if (m == l+1){
      slaev2f(d[l-1], e[l-1], d[l], rt1, rt2, c, s);
      rot2(z, l-1, c, s);
      d[l-1] = rt1; d[l] = rt2; e[l-1] = 0.f;
      l += 2;
      if (l <= lend) goto L40;
      goto L140;
    }
    if (jtot == nmaxit) goto L140;
    jtot++;
    g = (d[l] - p)/(2.f*e[l-1]);
    r = slapy2f(g, 1.f);
    g = d[m-1] - p + (e[l-1]/(g + copysignf(r, g)));
    s = 1.f; c = 1.f; p = 0.f;
    for (i = m-1; i >= l; --i){
      f = s*e[i-1];
      b = c*e[i-1];
      slartgf(g, f, c, s, r);
      if (i != m-1) e[i] = r;
      g = d[i] - p;
      r = (d[i-1] - g)*s + 2.f*c*b;
      p = s*r;
      d[i] = g + p;
      g = c*r - b;
      cw[i-l] = c; sw[i-l] = -s;
    }
    for (j = m-l; j >= 1; --j) rot2(z, l+j-2, cw[j-1], sw[j-1]);
    d[l-1] = d[l-1] - p;
    e[l-1] = g;
    goto L40;
L80:
    d[l-1] = p;
    l += 1;
    if (l <= lend) goto L40;
    goto L140;
  } else {
L90:
    if (l != lend){
      for (m = l; m >= lend+1; --m){
        tst = fabsf(e[m-2]); tst = tst*tst;
        if (tst <= (eps2*fabsf(d[m-1]))*fabsf(d[m-2]) + safmin) goto L110;
      }
    }
    m = lend;
L110:
    if (m > lend) e[m-2] = 0.f;
    p = d[l-1];
    if (m == l) goto L130;
    if (m == l-1){
      slaev2f(d[l-2], e[l-2], d[l-1], rt1, rt2, c, s);
      rot2(z, l-2, c, s);
      d[l-2] = rt1; d[l-1] = rt2; e[l-2] = 0.f;
      l -= 2;
      if (l >= lend) goto L90;
      goto L140;
    }
    if (jtot == nmaxit) goto L140;
    jtot++;
    g = (d[l-2] - p)/(2.f*e[l-2]);
    r = slapy2f(g, 1.f);
    g = d[m-1] - p + (e[l-2]/(g + copysignf(r, g)));
    s = 1.f; c = 1.f; p = 0.f;
    for (i = m; i <= l-1; ++i){
      f = s*e[i-1];
      b = c*e[i-1];
      slartgf(g, f, c, s, r);
      if (i != m) e[i-2] = r;
      g = d[i-1] - p;
      r = (d[i] - g)*s + 2.f*c*b;
      p = s*r;
      d[i-1] = g + p;
      g = c*r - b;
      cw[i-m] = c; sw[i-m] = s;
    }
    for (j = 1; j <= l-m; ++j) rot2(z, m+j-2, cw[j-1], sw[j-1]);
    d[l-1] = d[l-1] - p;
    e[l-2] = g;
    goto L90;
L130:
    d[l-1] = p;
    l -= 1;
    if (l >= lend) goto L90;
    goto L140;
  }
L140:
  if (iscale == 1){
    mul = anorm/ssfmax;
    for (i = lsv; i <= lendsv; ++i)   d[i-1] *= mul;
    for (i = lsv; i <= lendsv-1; ++i) e[i-1] *= mul;
  } else if (iscale == 2){
    mul = anorm/ssfmin;
    for (i = lsv; i <= lendsv; ++i)   d[i-1] *= mul;
    for (i = lsv; i <= lendsv-1; ++i) e[i-1] *= mul;
  }
  if (jtot < nmaxit) goto L10;
  return;
L160:
  for (ii = 2; ii <= n; ++ii){
    i = ii - 1; k = i; p = d[i-1];
    for (j = ii; j <= n; ++j){
      if (d[j-1] < p){ k = j; p = d[j-1]; }
    }
    if (k != i){
      d[k-1] = d[i-1]; d[i-1] = p;
      for (j = 0; j < 3; ++j){ float t = z[j][i-1]; z[j][i-1] = z[j][k-1]; z[j][k-1] = t; }
    }
  }
}

__device__ __noinline__ void eigh3_normal(float a11, float a21, float a31,
                                          float a22, float a32, float a33,
                                          float* out3){
#pragma clang fp contract(off)
  float d[3], e[2], z[3][3];
  float tau1 = 0.f, v2 = 0.f;
  float alpha = a21;
  float xnorm = fabsf(a31);
  if (xnorm == 0.f){
    e[0] = alpha;
    tau1 = 0.f;
  } else {
    float beta = -copysignf(slapy2f(alpha, xnorm), alpha);
    tau1 = (beta - alpha)/beta;
    v2 = a31*(1.f/(alpha - beta));
    float x1 = tau1*a22 + tau1*(a32*v2);
    float x2 = tau1*a32 + (tau1*v2)*a33;
    float al = -0.5f*tau1*(x1 + x2*v2);
    float w1 = x1 + al;
    float w2 = x2 + al*v2;
    a22 = a22 - w1 - w1;
    a32 = a32 - v2*w1 - w2;
    a33 = a33 - v2*w2 - w2*v2;
    e[0] = beta;
  }
  e[1] = a32;
  d[0] = a11; d[1] = a22; d[2] = a33;
  ssteqr3(d, e, z);
  if (tau1 != 0.f){
    #pragma unroll
    for (int jj = 0; jj < 3; ++jj){
      float wj  = z[1][jj] + v2*z[2][jj];
      float tmp = tau1*wj;
      z[1][jj] = z[1][jj] - tmp;
      z[2][jj] = z[2][jj] - v2*tmp;
    }
  }
  out3[0] = z[0][0]; out3[1] = z[1][0]; out3[2] = z[2][0];
}

// ---------------- helpers ----------------

__device__ __forceinline__ float sq3f(float x, float y, float z){
#pragma clang fp contract(off)
  return x*x + y*y + z*z;
}

__device__ __forceinline__ float d2f(float qs, float qx, float qy, float qz, float4 c){
#pragma clang fp contract(off)
  float dot = qx*c.x + qy*c.y + qz*c.z;
  return (qs + c.w) - 2.f*dot;
}

// ---------------- kernels ----------------

// Pack clouds as float4(x,y,z,sq). 65536 points total.
__global__ __launch_bounds__(256) void pack_kernel(const float* __restrict__ pred,
                                                   const float* __restrict__ gt,
                                                   float4* __restrict__ packed){
#pragma clang fp contract(off)
  int i = blockIdx.x*256 + threadIdx.x;        // 0..65535
  int cloud = i >> 13;                         // 0..7 (0-3 pred, 4-7 gt)
  int p = i & 8191;
  const float* base = ((cloud >> 2) ? gt : pred) + (size_t)(cloud & 3)*(NPTS*3);
  float x = base[p*3+0], y = base[p*3+1], z = base[p*3+2];
  packed[i] = make_float4(x, y, z, sq3f(x, y, z));
}

// One wave = 4 queries. Wave-shared top-16 per query (lanes 0-15, ascending
// lex (d2,idx)); candidates enter the serial insert chain only if
// dd <= thrA (analytic lambda=32 radius). If slot 15 is still sentinel after
// a scan, BAND-redo that query: rescan with thrOld < dd <= thrNew (keeps the
// accumulated exact list; union over rounds = all dd <= thrNew). 7 rounds =>
// thr > max possible d2 => full coverage => exactness guaranteed.
__global__ __launch_bounds__(256) void select_kernel(const float4* __restrict__ packed,
                                                     unsigned short* __restrict__ topk){
#pragma clang fp contract(off)
  const int tid  = threadIdx.x;
  const int lane = tid & 63;
  const int g    = blockIdx.x*4 + (tid >> 6);   // wave id 0..16383
  const int qbase = g*QPW;
  const int pc   = qbase >> 13;                 // cloud 0..7
  const float4* __restrict__ cp = packed + (size_t)pc*NPTS;
  const int q0 = qbase & 8191;

  float4 qv[QPW];
  #pragma unroll
  for (int k = 0; k < QPW; ++k) qv[k] = cp[q0 + k];

  // analytic threshold: target lambda=32 for N(0,1)^3 cloud, clamp for tails
  float thrA[QPW], thrO[QPW];
  #pragma unroll
  for (int k = 0; k < QPW; ++k){
    thrA[k] = fminf(0.0599f * __expf(qv[k].w * 0.33333334f), 0.8f);
    thrO[k] = -3.0e38f;                         // round-0 band: (-inf, thrA]
  }

  float bd[QPW]; int bi[QPW]; float t16[QPW]; int tI[QPW];
  bool done[QPW];
  #pragma unroll
  for (int k = 0; k < QPW; ++k) done[k] = false;

#define EV_INSERT(K, ddv, iv, passv) {                                        \
    unsigned long long m = __ballot(passv);                                   \
    while (m){                                                                \
      int s = __ffsll(m) - 1;                                                 \
      m &= m - 1;                                                             \
      float dds = __shfl((ddv), s);                                           \
      int idxs = (iv) + s;                                                    \
      if ((dds < t16[K]) || (dds == t16[K] && idxs < tI[K])){                 \
        bool less = (bd[K] < dds) || (bd[K] == dds && bi[K] < idxs);          \
        unsigned long long lm = __ballot(less) & 0xFFFFull;                   \
        int pos = __popcll(lm);                                               \
        float bup = __shfl_up(bd[K], 1);                                      \
        int   iup = __shfl_up(bi[K], 1);                                      \
        bool tn = (lane == pos);                                              \
        bool tu = (lane > pos) && (lane < 16);                                \
        bd[K] = tn ? dds  : (tu ? bup : bd[K]);                               \
        bi[K] = tn ? idxs : (tu ? iup : bi[K]);                               \
        t16[K] = __shfl(bd[K], 15);                                           \
        tI[K]  = __shfl(bi[K], 15);                                           \
      }                                                                       \
    }                                                                         \
  }

  // ---- round 0: all queries active; list/t16 init ----
  #pragma unroll
  for (int k = 0; k < QPW; ++k){
    bd[k] = 3.0e38f; bi[k] = 0x7fffffff; t16[k] = 3.0e38f; tI[k] = 0x7fffffff;
  }
  #pragma unroll 2
  for (int it = 0; it < NPTS/64; ++it){
    const int b0 = it*64;
    float4 cd = cp[b0 + lane];
    #pragma unroll
    for (int k = 0; k < QPW; ++k){
      float dd = d2f(qv[k].w, qv[k].x, qv[k].y, qv[k].z, cd);
      bool pass = dd <= thrA[k];
      EV_INSERT(k, dd, b0, pass)
    }
  }
  {
    bool anyUndone = false;
    #pragma unroll
    for (int k = 0; k < QPW; ++k){
      if (t16[k] < 3.0e38f) done[k] = true;
      else { thrO[k] = thrA[k]; thrA[k] = thrA[k]*2.5f + 1e-3f; anyUndone = true; }
    }
    // ---- band-redo rounds (rare; list accumulated, rescan only the band) ----
    for (int round = 1; round < 7 && anyUndone; ++round){
      #pragma unroll 2
      for (int it = 0; it < NPTS/64; ++it){
        const int b0 = it*64;
        float4 cd = cp[b0 + lane];
        #pragma unroll
        for (int k = 0; k < QPW; ++k){
          if (done[k]) continue;                 // wave-uniform branch
          float dd = d2f(qv[k].w, qv[k].x, qv[k].y, qv[k].z, cd);
          bool pass = (dd <= thrA[k]) && (dd > thrO[k]);   // exact band complement
          EV_INSERT(k, dd, b0, pass)
        }
      }
      anyUndone = false;
      #pragma unroll
      for (int k = 0; k < QPW; ++k) if (!done[k]){
        if (t16[k] < 3.0e38f) done[k] = true;
        else { thrO[k] = thrA[k]; thrA[k] = (round >= 5) ? 1.0e30f : thrA[k]*2.5f + 1e-3f; anyUndone = true; }
      }
    }
  }
#undef EV_INSERT

  if (lane < 16){
    #pragma unroll
    for (int k = 0; k < QPW; ++k)
      topk[(size_t)(qbase + k)*16 + lane] = (unsigned short)bi[k];
  }
}

// Thread per query: gather 16 neighbors (top_k order), covariance, eigh.
__global__ __launch_bounds__(256) void normal_kernel(const float4* __restrict__ packed,
                                                     const unsigned short* __restrict__ topk,
                                                     float* __restrict__ normals){
#pragma clang fp contract(off)
  const int gq = blockIdx.x*256 + threadIdx.x;   // 0..65535
  const int pc = gq >> 13;
  const float4* __restrict__ cp = packed + (size_t)pc*NPTS;
  const unsigned short* __restrict__ tk = topk + (size_t)gq*16;

  float gxx[16], gyy[16], gzz[16];
  #pragma unroll
  for (int r = 0; r < 16; ++r){
    float4 p = cp[tk[r]];
    gxx[r] = p.x; gyy[r] = p.y; gzz[r] = p.z;
  }
  float mx = 0.f, my = 0.f, mz = 0.f;
  #pragma unroll
  for (int r = 0; r < 16; ++r){ mx += gxx[r]; my += gyy[r]; mz += gzz[r]; }
  mx *= 0.0625f; my *= 0.0625f; mz *= 0.0625f;

  float c00=0.f, c10=0.f, c20=0.f, c11=0.f, c21=0.f, c22=0.f;
  #pragma unroll
  for (int r = 0; r < 16; ++r){
    float cx = gxx[r]-mx, cy = gyy[r]-my, cz = gzz[r]-mz;
    c00 += cx*cx; c10 += cy*cx; c20 += cz*cx;
    c11 += cy*cy; c21 += cz*cy; c22 += cz*cz;
  }
  c00 *= 0.0625f; c10 *= 0.0625f; c20 *= 0.0625f;
  c11 *= 0.0625f; c21 *= 0.0625f; c22 *= 0.0625f;

  float nrm[3];
  eigh3_normal(c00, c10, c20, c11, c21, c22, nrm);

  float* o = normals + (size_t)gq*3;
  o[0] = nrm[0]; o[1] = nrm[1]; o[2] = nrm[2];
}

// ---------------- loss ----------------

__global__ __launch_bounds__(256) void loss_partial(const float* __restrict__ normals,
                                                    float* __restrict__ partials){
  __shared__ float red[256];
  const float4* a4 = (const float4*)normals;                        // 24576 float4
  const float4* g4 = (const float4*)(normals + (size_t)NB*NPTS*3);
  float acc = 0.f;
  for (int i = blockIdx.x*256 + threadIdx.x; i < 24576; i += 64*256){
    float4 a = a4[i], g = g4[i];
    acc += a.x*g.x + a.y*g.y + a.z*g.z + a.w*g.w;
  }
  red[threadIdx.x] = acc;
  __syncthreads();
  for (int sft = 128; sft > 0; sft >>= 1){
    if (threadIdx.x < sft) red[threadIdx.x] += red[threadIdx.x + sft];
    __syncthreads();
  }
  if (threadIdx.x == 0) partials[blockIdx.x] = red[0];
}

__global__ void loss_final(const float* __restrict__ partials,
                           float* __restrict__ out){
  float v = partials[threadIdx.x];
  #pragma unroll
  for (int s = 32; s > 0; s >>= 1) v += __shfl_down(v, s, 64);
  if (threadIdx.x == 0) out[0] = 1.f - v*(1.f/32768.f);
}

extern "C" void kernel_launch(void* const* d_in, const int* in_sizes, int n_in,
                              void* d_out, int out_size, void* d_ws, size_t ws_size,
                              hipStream_t stream) {
  const float* pred = (const float*)d_in[0];
  const float* gt   = (const float*)d_in[1];
  // ws (floats): normals 196608 | partials 64 | packed 65536 float4 | topk 1M ushort
  float*          normals  = (float*)d_ws;
  float*          partials = normals + (size_t)2*NB*NPTS*3;
  float4*         packed   = (float4*)(partials + 64);        // 16B-aligned
  unsigned short* topk     = (unsigned short*)(packed + (size_t)8*NPTS);
  pack_kernel  <<<256,  256, 0, stream>>>(pred, gt, packed);
  select_kernel<<<4096, 256, 0, stream>>>(packed, topk);
  normal_kernel<<<256,  256, 0, stream>>>(packed, topk, normals);
  loss_partial <<<64,   256, 0, stream>>>(normals, partials);
  loss_final   <<<1,     64, 0, stream>>>(partials, (float*)d_out);
}